// Round 1
// baseline (1888.653 us; speedup 1.0000x reference)
//
#include <hip/hip_runtime.h>
#include <hip/hip_bf16.h>
#include <math.h>

// Problem constants
#define NROWS 65536
#define DIM   256
#define NCODE 8192
#define NTOPK 5

typedef __attribute__((ext_vector_type(8))) short     short8;
typedef __attribute__((ext_vector_type(4))) float     f32x4;
typedef __attribute__((ext_vector_type(4))) unsigned  u32x4;
typedef __attribute__((ext_vector_type(2))) unsigned  u32x2;

// ---- workspace layout (bytes) ----
#define WS_ESWZ   0u          // bf16 swizzled embed: 8192*512      = 4194304
#define WS_ENORM  4194304u    // f32 ||e||^2 per code: 8192*4       = 32768
#define WS_CAND   4227072u    // u16 cand[65536][16]                = 2097152
#define WS_IDX5   6324224u    // i32 [65536*5]                      = 1310720
#define WS_W5     7634944u    // f32 [65536*5]                      = 1310720
#define WS_ENCSUM 8945664u    // f32 [8192]                         = 32768
#define WS_CNT    8978432u    // u32 [8192]                         = 32768
#define WS_OFFS   9011200u    // u32 [8192]                         = 32768
#define WS_CURS   9043968u    // u32 [8192]                         = 32768
#define WS_SFAC   9076736u    // f32 scalars                        = 256
#define WS_ENTR   9076992u    // {u32 row, f32 w}[327680]           = 2621440
#define WS_NEWEMB 11698432u   // f32 [8192*256]                     = 8388608
// total ~19.2 MB

__device__ __forceinline__ unsigned short bf16r(float f) {
  unsigned u = __float_as_uint(f);
  return (unsigned short)((u + 0x7FFFu + ((u >> 16) & 1u)) >> 16);
}

__device__ __forceinline__ void gl_lds16(const void* g, void* l) {
  __builtin_amdgcn_global_load_lds(
      (const __attribute__((address_space(1))) unsigned int*)g,
      (__attribute__((address_space(3))) unsigned int*)l, 16, 0, 0);
}

// ============ K0: embed -> swizzled bf16 + ||e||^2 ============
__global__ __launch_bounds__(256) void k_prep(const float* __restrict__ embed,
                                              unsigned short* __restrict__ eswz,
                                              float* __restrict__ enorm) {
  const int code = blockIdx.x;
  const int d = threadIdx.x;
  float v = embed[code * DIM + d];
  __shared__ unsigned short rb[256];
  __shared__ double red[4];
  rb[d] = bf16r(v);
  double sq = (double)v * (double)v;
  #pragma unroll
  for (int off = 32; off; off >>= 1) sq += __shfl_down(sq, off);
  const int lane = d & 63, w = d >> 6;
  if (lane == 0) red[w] = sq;
  __syncthreads();
  if (d == 0) enorm[code] = (float)(red[0] + red[1] + red[2] + red[3]);
  if (d < 32) {
    const int c = d;
    const int cs = c ^ (code & 7);               // XOR-swizzle 16B chunks within 512B row
    u32x4 val = *(const u32x4*)&rb[c * 8];
    *(u32x4*)&eswz[code * 256 + cs * 8] = val;
  }
}

// ============ K1: fused bf16-MFMA score GEMM + per-lane top-4 candidates ============
struct List4 { float v0, v1, v2, v3; int i0, i1, i2, i3; };

__device__ __forceinline__ void insert4(List4& L, float m, int im) {
  bool g0 = m > L.v0, g1 = m > L.v1, g2 = m > L.v2, g3 = m > L.v3;
  float a0 = g0 ? m : L.v0;                 int b0 = g0 ? im : L.i0;
  float a1 = g1 ? (g0 ? L.v0 : m) : L.v1;   int b1 = g1 ? (g0 ? L.i0 : im) : L.i1;
  float a2 = g2 ? (g1 ? L.v1 : m) : L.v2;   int b2 = g2 ? (g1 ? L.i1 : im) : L.i2;
  float a3 = g3 ? (g2 ? L.v2 : m) : L.v3;   int b3 = g3 ? (g2 ? L.i2 : im) : L.i3;
  L.v0 = a0; L.v1 = a1; L.v2 = a2; L.v3 = a3;
  L.i0 = b0; L.i1 = b1; L.i2 = b2; L.i3 = b3;
}

__device__ __forceinline__ void select4(List4& L, f32x4 acc, f32x4 en, int cbase) {
  // score = dot - 0.5*||e||^2  (maximize)  == -(distance)/2 up to per-row const
  float v0 = fmaf(-0.5f, en[0], acc[0]);
  float v1 = fmaf(-0.5f, en[1], acc[1]);
  float v2 = fmaf(-0.5f, en[2], acc[2]);
  float v3 = fmaf(-0.5f, en[3], acc[3]);
  #pragma unroll 1
  for (int round = 0; round < 4; ++round) {
    float m01 = fmaxf(v0, v1); int r01 = (v1 > v0) ? 1 : 0;
    float m23 = fmaxf(v2, v3); int r23 = (v3 > v2) ? 3 : 2;
    float m = fmaxf(m01, m23); int rm = (m23 > m01) ? r23 : r01;
    if (!__any(m > L.v3)) break;
    insert4(L, m, cbase + rm);
    v0 = (rm == 0) ? -1e30f : v0;
    v1 = (rm == 1) ? -1e30f : v1;
    v2 = (rm == 2) ? -1e30f : v2;
    v3 = (rm == 3) ? -1e30f : v3;
  }
}

__global__ __launch_bounds__(256, 2) void k_gemm(const float* __restrict__ x,
                                                 const unsigned short* __restrict__ eswz,
                                                 const float* __restrict__ enorm,
                                                 unsigned short* __restrict__ cand) {
  __shared__ unsigned short ebuf[2][4096];   // 2 x 16 codes x 256 k (bf16), 8KB each
  __shared__ float enorm_s[NCODE];           // 32KB
  const int tid = threadIdx.x;
  const int wave = tid >> 6, lane = tid & 63;
  const int q = lane >> 4, ln = lane & 15;
  const int wrow0 = blockIdx.x * 128 + wave * 32;

  // async-stage enorm (32KB, 8 rounds) and code-tile 0
  #pragma unroll
  for (int r = 0; r < 8; ++r)
    gl_lds16(enorm + r * 1024 + tid * 4, &enorm_s[r * 1024 + tid * 4]);
  gl_lds16(eswz + tid * 8, &ebuf[0][tid * 8]);
  gl_lds16(eswz + 2048 + tid * 8, &ebuf[0][2048 + tid * 8]);

  // x fragments: 2 row-tiles x 8 k-steps, resident in VGPRs
  // B layout (16x16x32): lane holds B[k = 32s + 8q + j][n = ln]
  short8 xf[2][8];
  #pragma unroll
  for (int t = 0; t < 2; ++t) {
    const float* xr = x + (unsigned)(wrow0 + t * 16 + ln) * DIM;
    #pragma unroll
    for (int s = 0; s < 8; ++s) {
      f32x4 a = *(const f32x4*)(xr + s * 32 + q * 8);
      f32x4 b = *(const f32x4*)(xr + s * 32 + q * 8 + 4);
      short8 f;
      f[0] = (short)bf16r(a[0]); f[1] = (short)bf16r(a[1]);
      f[2] = (short)bf16r(a[2]); f[3] = (short)bf16r(a[3]);
      f[4] = (short)bf16r(b[0]); f[5] = (short)bf16r(b[1]);
      f[6] = (short)bf16r(b[2]); f[7] = (short)bf16r(b[3]);
      xf[t][s] = f;
    }
  }

  List4 L0 = {-3e38f, -3e38f, -3e38f, -3e38f, 0, 0, 0, 0};
  List4 L1 = L0;
  __syncthreads();

  int p = 0;
  #pragma unroll 1
  for (int it = 0; it < 512; ++it) {
    if (it + 1 < 512) {
      const unsigned short* src = eswz + (unsigned)(it + 1) * 4096;
      gl_lds16(src + tid * 8, &ebuf[p ^ 1][tid * 8]);
      gl_lds16(src + 2048 + tid * 8, &ebuf[p ^ 1][2048 + tid * 8]);
    }
    f32x4 acc0 = {0.f, 0.f, 0.f, 0.f}, acc1 = {0.f, 0.f, 0.f, 0.f};
    const unsigned short* eb = ebuf[p];
    #pragma unroll
    for (int s = 0; s < 8; ++s) {
      const int chunk = (4 * s + q) ^ (ln & 7);  // undo swizzle; conflict-free b128
      short8 ea = *(const short8*)&eb[ln * 256 + chunk * 8];
      acc0 = __builtin_amdgcn_mfma_f32_16x16x32_bf16(ea, xf[0][s], acc0, 0, 0, 0);
      acc1 = __builtin_amdgcn_mfma_f32_16x16x32_bf16(ea, xf[1][s], acc1, 0, 0, 0);
    }
    const int cbase = it * 16 + q * 4;           // codes for regs 0..3 (C row = q*4+r)
    f32x4 en = *(const f32x4*)&enorm_s[cbase];
    select4(L0, acc0, en, cbase);
    select4(L1, acc1, en, cbase);
    __syncthreads();
    p ^= 1;
  }

  // write 4 candidates per (row, quarter) as u16
  {
    const int row0 = wrow0 + ln;
    u32x2 pk;
    pk[0] = (unsigned)L0.i0 | ((unsigned)L0.i1 << 16);
    pk[1] = (unsigned)L0.i2 | ((unsigned)L0.i3 << 16);
    *(u32x2*)&cand[row0 * 16 + q * 4] = pk;
    const int row1 = wrow0 + 16 + ln;
    pk[0] = (unsigned)L1.i0 | ((unsigned)L1.i1 << 16);
    pk[1] = (unsigned)L1.i2 | ((unsigned)L1.i3 << 16);
    *(u32x2*)&cand[row1 * 16 + q * 4] = pk;
  }
}

// ============ K2: f64 exact re-score of 16 candidates, top-5 + softmax ============
__global__ __launch_bounds__(256) void k_refine(const float* __restrict__ x,
                                                const float* __restrict__ embed,
                                                const unsigned short* __restrict__ cand,
                                                float* __restrict__ out_idx,
                                                int* __restrict__ idx5,
                                                float* __restrict__ w5,
                                                float* __restrict__ enc_sum,
                                                unsigned* __restrict__ cnt) {
  const int wave = threadIdx.x >> 6, lane = threadIdx.x & 63;
  const int row = blockIdx.x * 4 + wave;
  const float* xr = x + (unsigned)row * DIM;
  const float x0 = xr[lane], x1 = xr[lane + 64], x2 = xr[lane + 128], x3 = xr[lane + 192];

  int cd[16];
  const unsigned* cp = (const unsigned*)(cand + row * 16);
  #pragma unroll
  for (int i = 0; i < 8; ++i) {
    unsigned v = cp[i];
    cd[2 * i] = (int)(v & 0xFFFFu);
    cd[2 * i + 1] = (int)(v >> 16);
  }

  double sc[16];
  #pragma unroll
  for (int ci = 0; ci < 16; ++ci) {
    const float* er = embed + (unsigned)cd[ci] * DIM;
    const float e0 = er[lane], e1 = er[lane + 64], e2 = er[lane + 128], e3 = er[lane + 192];
    double dot = (double)e0 * x0 + (double)e1 * x1 + (double)e2 * x2 + (double)e3 * x3;
    double ss  = (double)e0 * e0 + (double)e1 * e1 + (double)e2 * e2 + (double)e3 * e3;
    #pragma unroll
    for (int off = 1; off < 64; off <<= 1) {
      dot += __shfl_xor(dot, off);
      ss  += __shfl_xor(ss, off);
    }
    sc[ci] = ss - 2.0 * dot;   // distance minus per-row ||x||^2 (cancels everywhere)
  }

  // exact top-5, ties -> lower code index (matches lax.top_k / argmax semantics)
  unsigned used = 0;
  double bsv[5]; int bcd[5];
  #pragma unroll
  for (int j = 0; j < 5; ++j) {
    double best = 1e300; int bc = 1 << 30; int bci = 0;
    #pragma unroll
    for (int ci = 0; ci < 16; ++ci) {
      bool avail = ((used >> ci) & 1u) == 0;
      bool better = avail && (sc[ci] < best || (sc[ci] == best && cd[ci] < bc));
      if (better) { best = sc[ci]; bc = cd[ci]; bci = ci; }
    }
    used |= 1u << bci;
    bsv[j] = best; bcd[j] = bc;
  }
  double ex[5], sum = 0.0;
  #pragma unroll
  for (int j = 0; j < 5; ++j) { ex[j] = exp(-(bsv[j] - bsv[0])); sum += ex[j]; }

  if (lane == 0) {
    out_idx[row] = (float)bcd[0];
    #pragma unroll
    for (int j = 0; j < 5; ++j) {
      float w = (float)(ex[j] / sum);
      idx5[row * 5 + j] = bcd[j];
      w5[row * 5 + j] = w;
      atomicAdd(&enc_sum[bcd[j]], w);
      atomicAdd(&cnt[bcd[j]], 1u);
    }
  }
}

// ============ K3: scan counts -> CSR offsets, plus S factor ============
__global__ __launch_bounds__(256) void k_scan(const unsigned* __restrict__ cnt,
                                              unsigned* __restrict__ offs,
                                              unsigned* __restrict__ cursor,
                                              const float* __restrict__ enc_sum,
                                              const float* __restrict__ cluster_size,
                                              float* __restrict__ sfac) {
  __shared__ unsigned part[256];
  __shared__ double sred[256];
  const int t = threadIdx.x;
  unsigned s = 0;
  for (int i = 0; i < 32; ++i) s += cnt[t * 32 + i];
  part[t] = s;
  double ds = 0.0;
  for (int i = t; i < NCODE; i += 256)
    ds += 0.1 * (double)cluster_size[i] + 0.9 * (double)enc_sum[i];
  sred[t] = ds;
  __syncthreads();
  if (t == 0) {
    unsigned run = 0;
    for (int i = 0; i < 256; ++i) { unsigned tmp = part[i]; part[i] = run; run += tmp; }
    double S = 0.0;
    for (int i = 0; i < 256; ++i) S += sred[i];
    sfac[0] = (float)(S / (S + (double)NCODE * 1e-5));
  }
  __syncthreads();
  unsigned off = part[t];
  for (int i = 0; i < 32; ++i) {
    unsigned c = cnt[t * 32 + i];
    offs[t * 32 + i] = off;
    cursor[t * 32 + i] = off;
    off += c;
  }
}

// ============ K3b: fill CSR entries ============
__global__ __launch_bounds__(256) void k_fill(const int* __restrict__ idx5,
                                              const float* __restrict__ w5,
                                              unsigned* __restrict__ cursor,
                                              uint2* __restrict__ entries) {
  const int i = blockIdx.x * 256 + threadIdx.x;
  if (i >= NROWS * NTOPK) return;
  const int c = idx5[i];
  const float w = w5[i];
  const unsigned row = (unsigned)i / 5u;
  const unsigned slot = atomicAdd(&cursor[c], 1u);
  entries[slot] = make_uint2(row, __float_as_uint(w));
}

// ============ K4: per-code gather-accumulate -> new_embed ============
__global__ __launch_bounds__(256) void k_accum(const float* __restrict__ x,
                                               const uint2* __restrict__ entries,
                                               const unsigned* __restrict__ cnt,
                                               const unsigned* __restrict__ offs,
                                               const float* __restrict__ enc_sum,
                                               const float* __restrict__ cluster_size,
                                               const float* __restrict__ embed_avg,
                                               const float* __restrict__ sfac,
                                               float* __restrict__ newemb) {
  const int k = blockIdx.x, d = threadIdx.x;
  const unsigned n = cnt[k], o = offs[k];
  float acc = 0.f;
  for (unsigned i = 0; i < n; ++i) {
    uint2 e = entries[o + i];
    acc = fmaf(__uint_as_float(e.y), x[(unsigned)e.x * DIM + d], acc);
  }
  const float ncs = 0.1f * cluster_size[k] + 0.9f * enc_sum[k];
  const float cs = (ncs + 1e-5f) * sfac[0];
  newemb[(unsigned)k * DIM + d] = (0.1f * embed_avg[(unsigned)k * DIM + d] + 0.9f * acc) / cs;
}

// ============ K5: quantize = sum_j w_j * new_embed[idx_j] ============
__global__ __launch_bounds__(256) void k_quant(const int* __restrict__ idx5,
                                               const float* __restrict__ w5,
                                               const float* __restrict__ newemb,
                                               float* __restrict__ out) {
  const int d = threadIdx.x;
  const int rb = blockIdx.x * 16;
  for (int r = 0; r < 16; ++r) {
    const int row = rb + r;
    float acc = 0.f;
    #pragma unroll
    for (int j = 0; j < 5; ++j)
      acc = fmaf(w5[row * 5 + j], newemb[(unsigned)idx5[row * 5 + j] * DIM + d], acc);
    out[(unsigned)row * DIM + d] = acc;
  }
}

extern "C" void kernel_launch(void* const* d_in, const int* in_sizes, int n_in,
                              void* d_out, int out_size, void* d_ws, size_t ws_size,
                              hipStream_t stream) {
  const float* x            = (const float*)d_in[0];   // [65536,256]
  const float* embed        = (const float*)d_in[1];   // [8192,256]
  const float* cluster_size = (const float*)d_in[2];   // [8192]
  // d_in[3] cluster_sum unused for outputs
  const float* embed_avg    = (const float*)d_in[4];   // [8192,256]

  char* w = (char*)d_ws;
  unsigned short* eswz   = (unsigned short*)(w + WS_ESWZ);
  float*          enorm  = (float*)(w + WS_ENORM);
  unsigned short* cand   = (unsigned short*)(w + WS_CAND);
  int*            idx5   = (int*)(w + WS_IDX5);
  float*          w5     = (float*)(w + WS_W5);
  float*          encsum = (float*)(w + WS_ENCSUM);
  unsigned*       cnt    = (unsigned*)(w + WS_CNT);
  unsigned*       offs   = (unsigned*)(w + WS_OFFS);
  unsigned*       curs   = (unsigned*)(w + WS_CURS);
  float*          sfac   = (float*)(w + WS_SFAC);
  uint2*          entr   = (uint2*)(w + WS_ENTR);
  float*          newemb = (float*)(w + WS_NEWEMB);

  float* out_q   = (float*)d_out;                 // [65536*256]
  float* out_idx = out_q + (size_t)NROWS * DIM;   // [65536] as float

  // zero enc_sum + cnt (adjacent 64KB)
  hipMemsetAsync(w + WS_ENCSUM, 0, 65536, stream);

  k_prep<<<NCODE, 256, 0, stream>>>(embed, eswz, enorm);
  k_gemm<<<512, 256, 0, stream>>>(x, eswz, enorm, cand);
  k_refine<<<NROWS / 4, 256, 0, stream>>>(x, embed, cand, out_idx, idx5, w5, encsum, cnt);
  k_scan<<<1, 256, 0, stream>>>(cnt, offs, curs, encsum, cluster_size, sfac);
  k_fill<<<(NROWS * NTOPK + 255) / 256, 256, 0, stream>>>(idx5, w5, curs, entr);
  k_accum<<<NCODE, 256, 0, stream>>>(x, entr, cnt, offs, encsum, cluster_size, embed_avg, sfac, newemb);
  k_quant<<<NROWS / 16, 256, 0, stream>>>(idx5, w5, newemb, out_q);
}

// Round 2
// 926.238 us; speedup vs baseline: 2.0391x; 2.0391x over previous
//
#include <hip/hip_runtime.h>
#include <hip/hip_bf16.h>
#include <math.h>

// Problem constants
#define NROWS 65536
#define DIM   256
#define NCODE 8192
#define NTOPK 5

typedef __attribute__((ext_vector_type(8))) short     short8;
typedef __attribute__((ext_vector_type(4))) float     f32x4;
typedef __attribute__((ext_vector_type(4))) unsigned  u32x4;
typedef __attribute__((ext_vector_type(2))) unsigned  u32x2;

// ---- workspace layout (bytes) ----
#define WS_ESWZ   0u          // bf16 swizzled embed: 8192*512      = 4194304
#define WS_ENORM  4194304u    // f32 ||e||^2 per code: 8192*4       = 32768
#define WS_CAND   4227072u    // u16 cand[65536][16]                = 2097152
#define WS_IDX5   6324224u    // i32 [65536*5]                      = 1310720
#define WS_W5     7634944u    // f32 [65536*5]                      = 1310720
#define WS_ENCSUM 8945664u    // f32 [8192]                         = 32768
#define WS_CNT    8978432u    // u32 [8192]                         = 32768
#define WS_OFFS   9011200u    // u32 [8192]                         = 32768
#define WS_CURS   9043968u    // u32 [8192]                         = 32768
#define WS_SFAC   9076736u    // f32 scalars                        = 256
#define WS_ENTR   9076992u    // {u32 code<<16|row, f32 w}[327680]  = 2621440
#define WS_NEWEMB 11698432u   // f32 [8192*256] (embsum -> newemb in place) = 8388608
// total ~19.2 MB

#define ENT_PER_BLK 64
#define NENT (NROWS * NTOPK)

__device__ __forceinline__ unsigned short bf16r(float f) {
  unsigned u = __float_as_uint(f);
  return (unsigned short)((u + 0x7FFFu + ((u >> 16) & 1u)) >> 16);
}

__device__ __forceinline__ void gl_lds16(const void* g, void* l) {
  __builtin_amdgcn_global_load_lds(
      (const __attribute__((address_space(1))) unsigned int*)g,
      (__attribute__((address_space(3))) unsigned int*)l, 16, 0, 0);
}

// ============ K0: embed -> swizzled bf16 + ||e||^2 ============
__global__ __launch_bounds__(256) void k_prep(const float* __restrict__ embed,
                                              unsigned short* __restrict__ eswz,
                                              float* __restrict__ enorm) {
  const int code = blockIdx.x;
  const int d = threadIdx.x;
  float v = embed[code * DIM + d];
  __shared__ unsigned short rb[256];
  __shared__ double red[4];
  rb[d] = bf16r(v);
  double sq = (double)v * (double)v;
  #pragma unroll
  for (int off = 32; off; off >>= 1) sq += __shfl_down(sq, off);
  const int lane = d & 63, w = d >> 6;
  if (lane == 0) red[w] = sq;
  __syncthreads();
  if (d == 0) enorm[code] = (float)(red[0] + red[1] + red[2] + red[3]);
  if (d < 32) {
    const int c = d;
    const int cs = c ^ (code & 7);               // XOR-swizzle 16B chunks within 512B row
    u32x4 val = *(const u32x4*)&rb[c * 8];
    *(u32x4*)&eswz[code * 256 + cs * 8] = val;
  }
}

// ============ K1: fused bf16-MFMA score GEMM + per-lane top-4 candidates ============
struct List4 { float v0, v1, v2, v3; int i0, i1, i2, i3; };

__device__ __forceinline__ void insert4(List4& L, float m, int im) {
  bool g0 = m > L.v0, g1 = m > L.v1, g2 = m > L.v2, g3 = m > L.v3;
  float a0 = g0 ? m : L.v0;                 int b0 = g0 ? im : L.i0;
  float a1 = g1 ? (g0 ? L.v0 : m) : L.v1;   int b1 = g1 ? (g0 ? L.i0 : im) : L.i1;
  float a2 = g2 ? (g1 ? L.v1 : m) : L.v2;   int b2 = g2 ? (g1 ? L.i1 : im) : L.i2;
  float a3 = g3 ? (g2 ? L.v2 : m) : L.v3;   int b3 = g3 ? (g2 ? L.i2 : im) : L.i3;
  L.v0 = a0; L.v1 = a1; L.v2 = a2; L.v3 = a3;
  L.i0 = b0; L.i1 = b1; L.i2 = b2; L.i3 = b3;
}

__device__ __forceinline__ void select4(List4& L, f32x4 acc, f32x4 en, int cbase) {
  // score = dot - 0.5*||e||^2  (maximize)  == -(distance)/2 up to per-row const
  float v0 = fmaf(-0.5f, en[0], acc[0]);
  float v1 = fmaf(-0.5f, en[1], acc[1]);
  float v2 = fmaf(-0.5f, en[2], acc[2]);
  float v3 = fmaf(-0.5f, en[3], acc[3]);
  #pragma unroll 1
  for (int round = 0; round < 4; ++round) {
    float m01 = fmaxf(v0, v1); int r01 = (v1 > v0) ? 1 : 0;
    float m23 = fmaxf(v2, v3); int r23 = (v3 > v2) ? 3 : 2;
    float m = fmaxf(m01, m23); int rm = (m23 > m01) ? r23 : r01;
    if (!__any(m > L.v3)) break;
    insert4(L, m, cbase + rm);
    v0 = (rm == 0) ? -1e30f : v0;
    v1 = (rm == 1) ? -1e30f : v1;
    v2 = (rm == 2) ? -1e30f : v2;
    v3 = (rm == 3) ? -1e30f : v3;
  }
}

__global__ __launch_bounds__(256, 2) void k_gemm(const float* __restrict__ x,
                                                 const unsigned short* __restrict__ eswz,
                                                 const float* __restrict__ enorm,
                                                 unsigned short* __restrict__ cand) {
  __shared__ unsigned short ebuf[2][4096];   // 2 x 16 codes x 256 k (bf16), 8KB each
  __shared__ float enorm_s[NCODE];           // 32KB
  const int tid = threadIdx.x;
  const int wave = tid >> 6, lane = tid & 63;
  const int q = lane >> 4, ln = lane & 15;
  const int wrow0 = blockIdx.x * 128 + wave * 32;

  // async-stage enorm (32KB, 8 rounds) and code-tile 0
  #pragma unroll
  for (int r = 0; r < 8; ++r)
    gl_lds16(enorm + r * 1024 + tid * 4, &enorm_s[r * 1024 + tid * 4]);
  gl_lds16(eswz + tid * 8, &ebuf[0][tid * 8]);
  gl_lds16(eswz + 2048 + tid * 8, &ebuf[0][2048 + tid * 8]);

  // x fragments: 2 row-tiles x 8 k-steps, resident in VGPRs
  // B layout (16x16x32): lane holds B[k = 32s + 8q + j][n = ln]
  short8 xf[2][8];
  #pragma unroll
  for (int t = 0; t < 2; ++t) {
    const float* xr = x + (unsigned)(wrow0 + t * 16 + ln) * DIM;
    #pragma unroll
    for (int s = 0; s < 8; ++s) {
      f32x4 a = *(const f32x4*)(xr + s * 32 + q * 8);
      f32x4 b = *(const f32x4*)(xr + s * 32 + q * 8 + 4);
      short8 f;
      f[0] = (short)bf16r(a[0]); f[1] = (short)bf16r(a[1]);
      f[2] = (short)bf16r(a[2]); f[3] = (short)bf16r(a[3]);
      f[4] = (short)bf16r(b[0]); f[5] = (short)bf16r(b[1]);
      f[6] = (short)bf16r(b[2]); f[7] = (short)bf16r(b[3]);
      xf[t][s] = f;
    }
  }

  List4 L0 = {-3e38f, -3e38f, -3e38f, -3e38f, 0, 0, 0, 0};
  List4 L1 = L0;
  __syncthreads();

  int p = 0;
  #pragma unroll 1
  for (int it = 0; it < 512; ++it) {
    if (it + 1 < 512) {
      const unsigned short* src = eswz + (unsigned)(it + 1) * 4096;
      gl_lds16(src + tid * 8, &ebuf[p ^ 1][tid * 8]);
      gl_lds16(src + 2048 + tid * 8, &ebuf[p ^ 1][2048 + tid * 8]);
    }
    f32x4 acc0 = {0.f, 0.f, 0.f, 0.f}, acc1 = {0.f, 0.f, 0.f, 0.f};
    const unsigned short* eb = ebuf[p];
    #pragma unroll
    for (int s = 0; s < 8; ++s) {
      const int chunk = (4 * s + q) ^ (ln & 7);  // undo swizzle; conflict-free b128
      short8 ea = *(const short8*)&eb[ln * 256 + chunk * 8];
      acc0 = __builtin_amdgcn_mfma_f32_16x16x32_bf16(ea, xf[0][s], acc0, 0, 0, 0);
      acc1 = __builtin_amdgcn_mfma_f32_16x16x32_bf16(ea, xf[1][s], acc1, 0, 0, 0);
    }
    const int cbase = it * 16 + q * 4;           // codes for regs 0..3 (C row = q*4+r)
    f32x4 en = *(const f32x4*)&enorm_s[cbase];
    select4(L0, acc0, en, cbase);
    select4(L1, acc1, en, cbase);
    __syncthreads();
    p ^= 1;
  }

  // write 4 candidates per (row, quarter) as u16
  {
    const int row0 = wrow0 + ln;
    u32x2 pk;
    pk[0] = (unsigned)L0.i0 | ((unsigned)L0.i1 << 16);
    pk[1] = (unsigned)L0.i2 | ((unsigned)L0.i3 << 16);
    *(u32x2*)&cand[row0 * 16 + q * 4] = pk;
    const int row1 = wrow0 + 16 + ln;
    pk[0] = (unsigned)L1.i0 | ((unsigned)L1.i1 << 16);
    pk[1] = (unsigned)L1.i2 | ((unsigned)L1.i3 << 16);
    *(u32x2*)&cand[row1 * 16 + q * 4] = pk;
  }
}

// ============ K2: f64 exact re-score of 16 candidates, top-5 + softmax ============
__global__ __launch_bounds__(256) void k_refine(const float* __restrict__ x,
                                                const float* __restrict__ embed,
                                                const unsigned short* __restrict__ cand,
                                                float* __restrict__ out_idx,
                                                int* __restrict__ idx5,
                                                float* __restrict__ w5,
                                                float* __restrict__ enc_sum,
                                                unsigned* __restrict__ cnt) {
  const int wave = threadIdx.x >> 6, lane = threadIdx.x & 63;
  const int row = blockIdx.x * 4 + wave;
  const float* xr = x + (unsigned)row * DIM;
  const float x0 = xr[lane], x1 = xr[lane + 64], x2 = xr[lane + 128], x3 = xr[lane + 192];

  int cd[16];
  const unsigned* cp = (const unsigned*)(cand + row * 16);
  #pragma unroll
  for (int i = 0; i < 8; ++i) {
    unsigned v = cp[i];
    cd[2 * i] = (int)(v & 0xFFFFu);
    cd[2 * i + 1] = (int)(v >> 16);
  }

  double sc[16];
  #pragma unroll
  for (int ci = 0; ci < 16; ++ci) {
    const float* er = embed + (unsigned)cd[ci] * DIM;
    const float e0 = er[lane], e1 = er[lane + 64], e2 = er[lane + 128], e3 = er[lane + 192];
    double dot = (double)e0 * x0 + (double)e1 * x1 + (double)e2 * x2 + (double)e3 * x3;
    double ss  = (double)e0 * e0 + (double)e1 * e1 + (double)e2 * e2 + (double)e3 * e3;
    #pragma unroll
    for (int off = 1; off < 64; off <<= 1) {
      dot += __shfl_xor(dot, off);
      ss  += __shfl_xor(ss, off);
    }
    sc[ci] = ss - 2.0 * dot;   // distance minus per-row ||x||^2 (cancels everywhere)
  }

  // exact top-5, ties -> lower code index (matches lax.top_k / argmax semantics)
  unsigned used = 0;
  double bsv[5]; int bcd[5];
  #pragma unroll
  for (int j = 0; j < 5; ++j) {
    double best = 1e300; int bc = 1 << 30; int bci = 0;
    #pragma unroll
    for (int ci = 0; ci < 16; ++ci) {
      bool avail = ((used >> ci) & 1u) == 0;
      bool better = avail && (sc[ci] < best || (sc[ci] == best && cd[ci] < bc));
      if (better) { best = sc[ci]; bc = cd[ci]; bci = ci; }
    }
    used |= 1u << bci;
    bsv[j] = best; bcd[j] = bc;
  }
  double ex[5], sum = 0.0;
  #pragma unroll
  for (int j = 0; j < 5; ++j) { ex[j] = exp(-(bsv[j] - bsv[0])); sum += ex[j]; }

  if (lane == 0) {
    out_idx[row] = (float)bcd[0];
    #pragma unroll
    for (int j = 0; j < 5; ++j) {
      float w = (float)(ex[j] / sum);
      idx5[row * 5 + j] = bcd[j];
      w5[row * 5 + j] = w;
      atomicAdd(&enc_sum[bcd[j]], w);
      atomicAdd(&cnt[bcd[j]], 1u);
    }
  }
}

// ============ K3: scan counts -> CSR offsets, plus S factor ============
__global__ __launch_bounds__(256) void k_scan(const unsigned* __restrict__ cnt,
                                              unsigned* __restrict__ offs,
                                              unsigned* __restrict__ cursor,
                                              const float* __restrict__ enc_sum,
                                              const float* __restrict__ cluster_size,
                                              float* __restrict__ sfac) {
  __shared__ unsigned part[256];
  __shared__ double sred[256];
  const int t = threadIdx.x;
  unsigned s = 0;
  for (int i = 0; i < 32; ++i) s += cnt[t * 32 + i];
  part[t] = s;
  double ds = 0.0;
  for (int i = t; i < NCODE; i += 256)
    ds += 0.1 * (double)cluster_size[i] + 0.9 * (double)enc_sum[i];
  sred[t] = ds;
  __syncthreads();
  if (t == 0) {
    unsigned run = 0;
    for (int i = 0; i < 256; ++i) { unsigned tmp = part[i]; part[i] = run; run += tmp; }
    double S = 0.0;
    for (int i = 0; i < 256; ++i) S += sred[i];
    sfac[0] = (float)(S / (S + (double)NCODE * 1e-5));
  }
  __syncthreads();
  unsigned off = part[t];
  for (int i = 0; i < 32; ++i) {
    unsigned c = cnt[t * 32 + i];
    offs[t * 32 + i] = off;
    cursor[t * 32 + i] = off;
    off += c;
  }
}

// ============ K3b: fill CSR entries (meta = code<<16 | row) ============
__global__ __launch_bounds__(256) void k_fill(const int* __restrict__ idx5,
                                              const float* __restrict__ w5,
                                              unsigned* __restrict__ cursor,
                                              uint2* __restrict__ entries) {
  const int i = blockIdx.x * 256 + threadIdx.x;
  if (i >= NENT) return;
  const unsigned c = (unsigned)idx5[i];
  const float w = w5[i];
  const unsigned row = (unsigned)i / 5u;
  const unsigned slot = atomicAdd(&cursor[c], 1u);
  entries[slot] = make_uint2((c << 16) | row, __float_as_uint(w));
}

// ============ K4: flat segmented gather-accumulate (load-balanced) ============
// 5120 blocks x 64 entries each; thread d owns dim d; flush partial sum via
// atomicAdd at code boundaries (~1.6 codes per segment on average).
__global__ __launch_bounds__(256) void k_accum2(const float* __restrict__ x,
                                                const uint2* __restrict__ entries,
                                                float* __restrict__ embsum) {
  __shared__ uint2 ent[ENT_PER_BLK];
  const int t = threadIdx.x;
  const unsigned base = blockIdx.x * ENT_PER_BLK;
  if (t < ENT_PER_BLK * 2)
    ((unsigned*)ent)[t] = ((const unsigned*)(entries + base))[t];
  __syncthreads();

  float acc = 0.f;
  unsigned cur = ent[0].x >> 16;
  #pragma unroll 8
  for (int i = 0; i < ENT_PER_BLK; ++i) {
    const uint2 e = ent[i];
    const unsigned code = e.x >> 16;
    const unsigned row = e.x & 0xFFFFu;
    const float w = __uint_as_float(e.y);
    if (code != cur) {                       // block-uniform branch
      atomicAdd(&embsum[cur * DIM + t], acc);
      acc = 0.f; cur = code;
    }
    acc = fmaf(w, x[row * DIM + t], acc);
  }
  atomicAdd(&embsum[cur * DIM + t], acc);
}

// ============ K4b: normalize embsum -> new_embed (in place) ============
__global__ __launch_bounds__(256) void k_norm(const float* __restrict__ embed_avg,
                                              const float* __restrict__ cluster_size,
                                              const float* __restrict__ enc_sum,
                                              const float* __restrict__ sfac,
                                              float* __restrict__ embsum /* -> newemb */) {
  const int k = blockIdx.x, d = threadIdx.x;
  const float ncs = 0.1f * cluster_size[k] + 0.9f * enc_sum[k];
  const float cs = (ncs + 1e-5f) * sfac[0];
  const unsigned o = (unsigned)k * DIM + d;
  embsum[o] = (0.1f * embed_avg[o] + 0.9f * embsum[o]) / cs;
}

// ============ K5: quantize = sum_j w_j * new_embed[idx_j] ============
__global__ __launch_bounds__(256) void k_quant(const int* __restrict__ idx5,
                                               const float* __restrict__ w5,
                                               const float* __restrict__ newemb,
                                               float* __restrict__ out) {
  const int d = threadIdx.x;
  const int rb = blockIdx.x * 16;
  for (int r = 0; r < 16; ++r) {
    const int row = rb + r;
    float acc = 0.f;
    #pragma unroll
    for (int j = 0; j < 5; ++j)
      acc = fmaf(w5[row * 5 + j], newemb[(unsigned)idx5[row * 5 + j] * DIM + d], acc);
    out[(unsigned)row * DIM + d] = acc;
  }
}

extern "C" void kernel_launch(void* const* d_in, const int* in_sizes, int n_in,
                              void* d_out, int out_size, void* d_ws, size_t ws_size,
                              hipStream_t stream) {
  const float* x            = (const float*)d_in[0];   // [65536,256]
  const float* embed        = (const float*)d_in[1];   // [8192,256]
  const float* cluster_size = (const float*)d_in[2];   // [8192]
  // d_in[3] cluster_sum unused for outputs
  const float* embed_avg    = (const float*)d_in[4];   // [8192,256]

  char* w = (char*)d_ws;
  unsigned short* eswz   = (unsigned short*)(w + WS_ESWZ);
  float*          enorm  = (float*)(w + WS_ENORM);
  unsigned short* cand   = (unsigned short*)(w + WS_CAND);
  int*            idx5   = (int*)(w + WS_IDX5);
  float*          w5     = (float*)(w + WS_W5);
  float*          encsum = (float*)(w + WS_ENCSUM);
  unsigned*       cnt    = (unsigned*)(w + WS_CNT);
  unsigned*       offs   = (unsigned*)(w + WS_OFFS);
  unsigned*       curs   = (unsigned*)(w + WS_CURS);
  float*          sfac   = (float*)(w + WS_SFAC);
  uint2*          entr   = (uint2*)(w + WS_ENTR);
  float*          embsum = (float*)(w + WS_NEWEMB);    // zeroed -> accum -> normalized in place

  float* out_q   = (float*)d_out;                 // [65536*256]
  float* out_idx = out_q + (size_t)NROWS * DIM;   // [65536] as float

  // zero enc_sum + cnt (adjacent 64KB) and embsum (8MB)
  hipMemsetAsync(w + WS_ENCSUM, 0, 65536, stream);
  hipMemsetAsync(w + WS_NEWEMB, 0, (size_t)NCODE * DIM * 4, stream);

  k_prep<<<NCODE, 256, 0, stream>>>(embed, eswz, enorm);
  k_gemm<<<512, 256, 0, stream>>>(x, eswz, enorm, cand);
  k_refine<<<NROWS / 4, 256, 0, stream>>>(x, embed, cand, out_idx, idx5, w5, encsum, cnt);
  k_scan<<<1, 256, 0, stream>>>(cnt, offs, curs, encsum, cluster_size, sfac);
  k_fill<<<(NENT + 255) / 256, 256, 0, stream>>>(idx5, w5, curs, entr);
  k_accum2<<<NENT / ENT_PER_BLK, 256, 0, stream>>>(x, entr, embsum);
  k_norm<<<NCODE, 256, 0, stream>>>(embed_avg, cluster_size, encsum, sfac, embsum);
  k_quant<<<NROWS / 16, 256, 0, stream>>>(idx5, w5, embsum, out_q);
}

// Round 3
// 766.015 us; speedup vs baseline: 2.4656x; 1.2092x over previous
//
#include <hip/hip_runtime.h>
#include <hip/hip_bf16.h>
#include <math.h>

// Problem constants
#define NROWS 65536
#define DIM   256
#define NCODE 8192
#define NTOPK 5

typedef __attribute__((ext_vector_type(8))) short     short8;
typedef __attribute__((ext_vector_type(4))) float     f32x4;
typedef __attribute__((ext_vector_type(4))) unsigned  u32x4;
typedef __attribute__((ext_vector_type(2))) unsigned  u32x2;

// ---- workspace layout (bytes) ----
#define WS_ESWZ   0u          // bf16 swizzled embed: 8192*512      = 4194304
#define WS_ENORM  4194304u    // f32 -64*||e||^2 per code: 8192*4   = 32768
#define WS_CAND   4227072u    // u16 cand[65536][16]                = 2097152
#define WS_IDX5   6324224u    // i32 [65536*5]                      = 1310720
#define WS_W5     7634944u    // f32 [65536*5]                      = 1310720
#define WS_ENCSUM 8945664u    // f32 [8192]                         = 32768
#define WS_CNT    8978432u    // u32 [8192]                         = 32768
#define WS_OFFS   9011200u    // u32 [8192]                         = 32768
#define WS_CURS   9043968u    // u32 [8192]                         = 32768
#define WS_SFAC   9076736u    // f32 scalars                        = 256
#define WS_ENTR   9076992u    // {u32 code<<16|row, f32 w}[327680]  = 2621440
#define WS_NEWEMB 11698432u   // f32 [8192*256] (embsum -> newemb in place) = 8388608
// total ~19.2 MB

#define ENT_PER_BLK 64
#define NENT (NROWS * NTOPK)

__device__ __forceinline__ unsigned short bf16r(float f) {
  unsigned u = __float_as_uint(f);
  return (unsigned short)((u + 0x7FFFu + ((u >> 16) & 1u)) >> 16);
}

__device__ __forceinline__ void gl_lds16(const void* g, void* l) {
  __builtin_amdgcn_global_load_lds(
      (const __attribute__((address_space(1))) unsigned int*)g,
      (__attribute__((address_space(3))) unsigned int*)l, 16, 0, 0);
}

// ============ K0: embed -> swizzled bf16 + (-64*||e||^2) ============
__global__ __launch_bounds__(256) void k_prep(const float* __restrict__ embed,
                                              unsigned short* __restrict__ eswz,
                                              float* __restrict__ enorm4) {
  const int code = blockIdx.x;
  const int d = threadIdx.x;
  float v = embed[code * DIM + d];
  __shared__ unsigned short rb[256];
  __shared__ double red[4];
  rb[d] = bf16r(v);
  double sq = (double)v * (double)v;
  #pragma unroll
  for (int off = 32; off; off >>= 1) sq += __shfl_down(sq, off);
  const int lane = d & 63, w = d >> 6;
  if (lane == 0) red[w] = sq;
  __syncthreads();
  if (d == 0) enorm4[code] = (float)(-64.0 * (red[0] + red[1] + red[2] + red[3]));
  if (d < 32) {
    const int c = d;
    const int cs = c ^ (code & 7);               // XOR-swizzle 16B chunks within 512B row
    u32x4 val = *(const u32x4*)&rb[c * 8];
    *(u32x4*)&eswz[code * 256 + cs * 8] = val;
  }
}

// ============ K1: barrier-light bf16-MFMA score GEMM + packed-int top-4 ============
// acc = 128*dot(x,e) - 64*||e||^2 = 128*score  (via C-init and 128x-scaled x frags)
// packed key = (int)acc * 8192 + code  -> top-4 per (row, lane-quarter) via min/max ladder

struct PList { int a, b, c, d; };

__device__ __forceinline__ void ladder(PList& P, int t) {
  int c0 = min(P.a, t); P.a = max(P.a, t);
  int c1 = min(P.b, c0); P.b = max(P.b, c0);
  int c2 = min(P.c, c1); P.c = max(P.c, c1);
  P.d = max(P.d, c2);
}

__device__ __forceinline__ void psel(PList& P, f32x4 acc, int cb) {
  int p0 = (int)acc[0] * 8192 + cb;
  int p1 = (int)acc[1] * 8192 + cb + 1;
  int p2 = (int)acc[2] * 8192 + cb + 2;
  int p3 = (int)acc[3] * 8192 + cb + 3;
  int h1 = max(p0, p1), l1 = min(p0, p1);
  int h2 = max(p2, p3), l2 = min(p2, p3);
  int t1 = max(h1, h2);
  int t2 = max(min(h1, h2), max(l1, l2));
  ladder(P, t1);
  if (__any(t2 > P.d)) ladder(P, t2);      // rare: 2 top-4 codes in same 4-tile
}

__global__ __launch_bounds__(256, 2) void k_gemm(const float* __restrict__ x,
                                                 const unsigned short* __restrict__ eswz,
                                                 const float* __restrict__ enorm4,
                                                 unsigned short* __restrict__ cand) {
  __shared__ unsigned short ebuf[3][8192];   // ring: 3 slots x (32 codes x 256 k bf16, 16KB)
  __shared__ float enorm_s[NCODE];           // 32KB  (total LDS 80KB -> 2 blocks/CU)
  const int tid = threadIdx.x;
  const int lane = tid & 63, wave = tid >> 6;
  const int q = lane >> 4, ln = lane & 15;
  const int wrow0 = blockIdx.x * 128 + wave * 32;

  // stage enorm (8 rounds) + code-tile 0 into slot 0
  #pragma unroll
  for (int r = 0; r < 8; ++r)
    gl_lds16(enorm4 + r * 1024 + tid * 4, &enorm_s[r * 1024 + tid * 4]);
  #pragma unroll
  for (int r = 0; r < 4; ++r)
    gl_lds16(eswz + r * 2048 + tid * 8, &ebuf[0][r * 2048 + tid * 8]);

  // x fragments (x128 scale), resident in VGPRs.
  // B layout (16x16x32): lane holds B[k = 32s + 8q + j][n = ln]
  short8 xf[2][8];
  #pragma unroll
  for (int t = 0; t < 2; ++t) {
    const float* xr = x + (unsigned)(wrow0 + t * 16 + ln) * DIM;
    #pragma unroll
    for (int s = 0; s < 8; ++s) {
      f32x4 a = *(const f32x4*)(xr + s * 32 + q * 8);
      f32x4 b = *(const f32x4*)(xr + s * 32 + q * 8 + 4);
      short8 f;
      f[0] = (short)bf16r(128.f * a[0]); f[1] = (short)bf16r(128.f * a[1]);
      f[2] = (short)bf16r(128.f * a[2]); f[3] = (short)bf16r(128.f * a[3]);
      f[4] = (short)bf16r(128.f * b[0]); f[5] = (short)bf16r(128.f * b[1]);
      f[6] = (short)bf16r(128.f * b[2]); f[7] = (short)bf16r(128.f * b[3]);
      xf[t][s] = f;
    }
  }

  PList P0 = {INT_MIN, INT_MIN, INT_MIN, INT_MIN};
  PList P1 = P0;

  int slot = 0;
  #pragma unroll 1
  for (int it = 0; it < 256; ++it) {
    const int nslot = (slot + 1 == 3) ? 0 : slot + 1;
    const int tl = (it < 255) ? it + 1 : 255;           // clamp: tail reload harmless
    const unsigned short* src = eswz + (unsigned)tl * 8192;
    #pragma unroll
    for (int r = 0; r < 4; ++r)
      gl_lds16(src + r * 2048 + tid * 8, &ebuf[nslot][r * 2048 + tid * 8]);

    // counted wait: 4 just-issued loads may stay in flight; tile `it` is done.
    asm volatile("s_waitcnt vmcnt(4)\n\ts_barrier" ::: "memory");

    #pragma unroll
    for (int c = 0; c < 2; ++c) {
      const int cbase = it * 32 + c * 16 + q * 4;
      f32x4 en = *(const f32x4*)&enorm_s[cbase];        // broadcast, conflict-free
      f32x4 acc0 = en, acc1 = en;                       // C-init = -64*||e||^2
      const unsigned short* eb = &ebuf[slot][c * 4096];
      #pragma unroll
      for (int s = 0; s < 8; ++s) {
        const int chunk = (4 * s + q) ^ (ln & 7);       // undo swizzle
        short8 ea = *(const short8*)&eb[ln * 256 + chunk * 8];
        acc0 = __builtin_amdgcn_mfma_f32_16x16x32_bf16(ea, xf[0][s], acc0, 0, 0, 0);
        acc1 = __builtin_amdgcn_mfma_f32_16x16x32_bf16(ea, xf[1][s], acc1, 0, 0, 0);
      }
      psel(P0, acc0, cbase);
      psel(P1, acc1, cbase);
    }
    slot = nslot;
  }

  // write 4 candidate codes per (row, quarter) as u16
  {
    const int row0 = wrow0 + ln;
    u32x2 pk;
    pk[0] = ((unsigned)P0.a & 8191u) | (((unsigned)P0.b & 8191u) << 16);
    pk[1] = ((unsigned)P0.c & 8191u) | (((unsigned)P0.d & 8191u) << 16);
    *(u32x2*)&cand[row0 * 16 + q * 4] = pk;
    const int row1 = wrow0 + 16 + ln;
    pk[0] = ((unsigned)P1.a & 8191u) | (((unsigned)P1.b & 8191u) << 16);
    pk[1] = ((unsigned)P1.c & 8191u) | (((unsigned)P1.d & 8191u) << 16);
    *(u32x2*)&cand[row1 * 16 + q * 4] = pk;
  }
}

// ============ K2: f64 exact re-score of 16 candidates, top-5 + softmax ============
__global__ __launch_bounds__(256) void k_refine(const float* __restrict__ x,
                                                const float* __restrict__ embed,
                                                const unsigned short* __restrict__ cand,
                                                float* __restrict__ out_idx,
                                                int* __restrict__ idx5,
                                                float* __restrict__ w5,
                                                float* __restrict__ enc_sum,
                                                unsigned* __restrict__ cnt) {
  const int wave = threadIdx.x >> 6, lane = threadIdx.x & 63;
  const int row = blockIdx.x * 4 + wave;
  const float* xr = x + (unsigned)row * DIM;
  const float x0 = xr[lane], x1 = xr[lane + 64], x2 = xr[lane + 128], x3 = xr[lane + 192];

  int cd[16];
  const unsigned* cp = (const unsigned*)(cand + row * 16);
  #pragma unroll
  for (int i = 0; i < 8; ++i) {
    unsigned v = cp[i];
    cd[2 * i] = (int)(v & 0xFFFFu);
    cd[2 * i + 1] = (int)(v >> 16);
  }

  double sc[16];
  #pragma unroll
  for (int ci = 0; ci < 16; ++ci) {
    const float* er = embed + (unsigned)cd[ci] * DIM;
    const float e0 = er[lane], e1 = er[lane + 64], e2 = er[lane + 128], e3 = er[lane + 192];
    double dot = (double)e0 * x0 + (double)e1 * x1 + (double)e2 * x2 + (double)e3 * x3;
    double ss  = (double)e0 * e0 + (double)e1 * e1 + (double)e2 * e2 + (double)e3 * e3;
    #pragma unroll
    for (int off = 1; off < 64; off <<= 1) {
      dot += __shfl_xor(dot, off);
      ss  += __shfl_xor(ss, off);
    }
    sc[ci] = ss - 2.0 * dot;   // distance minus per-row ||x||^2 (cancels everywhere)
  }

  // exact top-5, ties -> lower code index (matches lax.top_k / argmax semantics)
  unsigned used = 0;
  double bsv[5]; int bcd[5];
  #pragma unroll
  for (int j = 0; j < 5; ++j) {
    double best = 1e300; int bc = 1 << 30; int bci = 0;
    #pragma unroll
    for (int ci = 0; ci < 16; ++ci) {
      bool avail = ((used >> ci) & 1u) == 0;
      bool better = avail && (sc[ci] < best || (sc[ci] == best && cd[ci] < bc));
      if (better) { best = sc[ci]; bc = cd[ci]; bci = ci; }
    }
    used |= 1u << bci;
    bsv[j] = best; bcd[j] = bc;
  }
  double ex[5], sum = 0.0;
  #pragma unroll
  for (int j = 0; j < 5; ++j) { ex[j] = exp(-(bsv[j] - bsv[0])); sum += ex[j]; }

  if (lane == 0) {
    out_idx[row] = (float)bcd[0];
    #pragma unroll
    for (int j = 0; j < 5; ++j) {
      float w = (float)(ex[j] / sum);
      idx5[row * 5 + j] = bcd[j];
      w5[row * 5 + j] = w;
      atomicAdd(&enc_sum[bcd[j]], w);
      atomicAdd(&cnt[bcd[j]], 1u);
    }
  }
}

// ============ K3: scan counts -> CSR offsets, plus S factor ============
__global__ __launch_bounds__(256) void k_scan(const unsigned* __restrict__ cnt,
                                              unsigned* __restrict__ offs,
                                              unsigned* __restrict__ cursor,
                                              const float* __restrict__ enc_sum,
                                              const float* __restrict__ cluster_size,
                                              float* __restrict__ sfac) {
  __shared__ unsigned part[256];
  __shared__ double sred[256];
  const int t = threadIdx.x;
  unsigned s = 0;
  for (int i = 0; i < 32; ++i) s += cnt[t * 32 + i];
  part[t] = s;
  double ds = 0.0;
  for (int i = t; i < NCODE; i += 256)
    ds += 0.1 * (double)cluster_size[i] + 0.9 * (double)enc_sum[i];
  sred[t] = ds;
  __syncthreads();
  if (t == 0) {
    unsigned run = 0;
    for (int i = 0; i < 256; ++i) { unsigned tmp = part[i]; part[i] = run; run += tmp; }
    double S = 0.0;
    for (int i = 0; i < 256; ++i) S += sred[i];
    sfac[0] = (float)(S / (S + (double)NCODE * 1e-5));
  }
  __syncthreads();
  unsigned off = part[t];
  for (int i = 0; i < 32; ++i) {
    unsigned c = cnt[t * 32 + i];
    offs[t * 32 + i] = off;
    cursor[t * 32 + i] = off;
    off += c;
  }
}

// ============ K3b: fill CSR entries (meta = code<<16 | row) ============
__global__ __launch_bounds__(256) void k_fill(const int* __restrict__ idx5,
                                              const float* __restrict__ w5,
                                              unsigned* __restrict__ cursor,
                                              uint2* __restrict__ entries) {
  const int i = blockIdx.x * 256 + threadIdx.x;
  if (i >= NENT) return;
  const unsigned c = (unsigned)idx5[i];
  const float w = w5[i];
  const unsigned row = (unsigned)i / 5u;
  const unsigned slot = atomicAdd(&cursor[c], 1u);
  entries[slot] = make_uint2((c << 16) | row, __float_as_uint(w));
}

// ============ K4: flat segmented gather-accumulate (load-balanced) ============
__global__ __launch_bounds__(256) void k_accum2(const float* __restrict__ x,
                                                const uint2* __restrict__ entries,
                                                float* __restrict__ embsum) {
  __shared__ uint2 ent[ENT_PER_BLK];
  const int t = threadIdx.x;
  const unsigned base = blockIdx.x * ENT_PER_BLK;
  if (t < ENT_PER_BLK * 2)
    ((unsigned*)ent)[t] = ((const unsigned*)(entries + base))[t];
  __syncthreads();

  float acc = 0.f;
  unsigned cur = ent[0].x >> 16;
  #pragma unroll 8
  for (int i = 0; i < ENT_PER_BLK; ++i) {
    const uint2 e = ent[i];
    const unsigned code = e.x >> 16;
    const unsigned row = e.x & 0xFFFFu;
    const float w = __uint_as_float(e.y);
    if (code != cur) {                       // block-uniform branch
      atomicAdd(&embsum[cur * DIM + t], acc);
      acc = 0.f; cur = code;
    }
    acc = fmaf(w, x[row * DIM + t], acc);
  }
  atomicAdd(&embsum[cur * DIM + t], acc);
}

// ============ K4b: normalize embsum -> new_embed (in place) ============
__global__ __launch_bounds__(256) void k_norm(const float* __restrict__ embed_avg,
                                              const float* __restrict__ cluster_size,
                                              const float* __restrict__ enc_sum,
                                              const float* __restrict__ sfac,
                                              float* __restrict__ embsum /* -> newemb */) {
  const int k = blockIdx.x, d = threadIdx.x;
  const float ncs = 0.1f * cluster_size[k] + 0.9f * enc_sum[k];
  const float cs = (ncs + 1e-5f) * sfac[0];
  const unsigned o = (unsigned)k * DIM + d;
  embsum[o] = (0.1f * embed_avg[o] + 0.9f * embsum[o]) / cs;
}

// ============ K5: quantize = sum_j w_j * new_embed[idx_j] ============
__global__ __launch_bounds__(256) void k_quant(const int* __restrict__ idx5,
                                               const float* __restrict__ w5,
                                               const float* __restrict__ newemb,
                                               float* __restrict__ out) {
  const int d = threadIdx.x;
  const int rb = blockIdx.x * 16;
  for (int r = 0; r < 16; ++r) {
    const int row = rb + r;
    float acc = 0.f;
    #pragma unroll
    for (int j = 0; j < 5; ++j)
      acc = fmaf(w5[row * 5 + j], newemb[(unsigned)idx5[row * 5 + j] * DIM + d], acc);
    out[(unsigned)row * DIM + d] = acc;
  }
}

extern "C" void kernel_launch(void* const* d_in, const int* in_sizes, int n_in,
                              void* d_out, int out_size, void* d_ws, size_t ws_size,
                              hipStream_t stream) {
  const float* x            = (const float*)d_in[0];   // [65536,256]
  const float* embed        = (const float*)d_in[1];   // [8192,256]
  const float* cluster_size = (const float*)d_in[2];   // [8192]
  // d_in[3] cluster_sum unused for outputs
  const float* embed_avg    = (const float*)d_in[4];   // [8192,256]

  char* w = (char*)d_ws;
  unsigned short* eswz   = (unsigned short*)(w + WS_ESWZ);
  float*          enorm4 = (float*)(w + WS_ENORM);
  unsigned short* cand   = (unsigned short*)(w + WS_CAND);
  int*            idx5   = (int*)(w + WS_IDX5);
  float*          w5     = (float*)(w + WS_W5);
  float*          encsum = (float*)(w + WS_ENCSUM);
  unsigned*       cnt    = (unsigned*)(w + WS_CNT);
  unsigned*       offs   = (unsigned*)(w + WS_OFFS);
  unsigned*       curs   = (unsigned*)(w + WS_CURS);
  float*          sfac   = (float*)(w + WS_SFAC);
  uint2*          entr   = (uint2*)(w + WS_ENTR);
  float*          embsum = (float*)(w + WS_NEWEMB);    // zeroed -> accum -> normalized in place

  float* out_q   = (float*)d_out;                 // [65536*256]
  float* out_idx = out_q + (size_t)NROWS * DIM;   // [65536] as float

  // zero enc_sum + cnt (adjacent 64KB) and embsum (8MB)
  hipMemsetAsync(w + WS_ENCSUM, 0, 65536, stream);
  hipMemsetAsync(w + WS_NEWEMB, 0, (size_t)NCODE * DIM * 4, stream);

  k_prep<<<NCODE, 256, 0, stream>>>(embed, eswz, enorm4);
  k_gemm<<<512, 256, 0, stream>>>(x, eswz, enorm4, cand);
  k_refine<<<NROWS / 4, 256, 0, stream>>>(x, embed, cand, out_idx, idx5, w5, encsum, cnt);
  k_scan<<<1, 256, 0, stream>>>(cnt, offs, curs, encsum, cluster_size, sfac);
  k_fill<<<(NENT + 255) / 256, 256, 0, stream>>>(idx5, w5, curs, entr);
  k_accum2<<<NENT / ENT_PER_BLK, 256, 0, stream>>>(x, entr, embsum);
  k_norm<<<NCODE, 256, 0, stream>>>(embed_avg, cluster_size, encsum, sfac, embsum);
  k_quant<<<NROWS / 16, 256, 0, stream>>>(idx5, w5, embsum, out_q);
}

// Round 4
// 485.456 us; speedup vs baseline: 3.8905x; 1.5779x over previous
//
#include <hip/hip_runtime.h>
#include <hip/hip_bf16.h>
#include <math.h>
#include <limits.h>

// Problem constants
#define NROWS 65536
#define DIM   256
#define NCODE 8192
#define NTOPK 5

typedef __attribute__((ext_vector_type(4))) float     f32x4;
typedef __attribute__((ext_vector_type(4))) int       i32x4;
typedef __attribute__((ext_vector_type(2))) unsigned  u32x2;

// ---- workspace layout (bytes) ----
#define WS_ESWZ   0u          // i8 swizzled embed: 8192*256        = 2097152
#define WS_CINIT  2097152u    // i32 -(||16e||^2 >> 1) per code     = 32768
#define WS_CAND   2129920u    // u16 cand[65536][16]                = 2097152
#define WS_IDX5   4227072u    // i32 [65536*5]                      = 1310720
#define WS_W5     5537792u    // f32 [65536*5]                      = 1310720
#define WS_ENCSUM 6848512u    // f32 [8192]                         = 32768
#define WS_CNT    6881280u    // u32 [8192]                         = 32768
#define WS_OFFS   6914048u    // u32 [8192]                         = 32768
#define WS_CURS   6946816u    // u32 [8192]                         = 32768
#define WS_SFAC   6979584u    // f32 scalars                        = 256
#define WS_ENTR   6979840u    // {u32 code<<16|row, f32 w}[327680]  = 2621440
#define WS_NEWEMB 9601280u    // f32 [8192*256] (embsum->newemb in place) = 8388608
// total ~18 MB

#define ENT_PER_BLK 64
#define NENT (NROWS * NTOPK)

__device__ __forceinline__ void gl_lds16(const void* g, void* l) {
  __builtin_amdgcn_global_load_lds(
      (const __attribute__((address_space(1))) unsigned int*)g,
      (__attribute__((address_space(3))) unsigned int*)l, 16, 0, 0);
}

// monotonic u32 key for f32 (ascending float <-> ascending unsigned)
__device__ __forceinline__ unsigned f2key(float f) {
  unsigned u = __float_as_uint(f);
  return (u & 0x80000000u) ? ~u : (u | 0x80000000u);
}
__device__ __forceinline__ float key2f(unsigned k) {
  unsigned u = (k & 0x80000000u) ? (k ^ 0x80000000u) : ~k;
  return __uint_as_float(u);
}

// ============ K0: embed -> swizzled i8 (scale 16) + C-init table ============
__global__ __launch_bounds__(256) void k_prep(const float* __restrict__ embed,
                                              signed char* __restrict__ eswz,
                                              int* __restrict__ cinit) {
  const int code = blockIdx.x;
  const int d = threadIdx.x;
  float v = embed[code * DIM + d];
  float qf = fminf(127.f, fmaxf(-127.f, rintf(16.f * v)));
  int q = (int)qf;
  __shared__ unsigned char rb[256];
  __shared__ int red[4];
  rb[d] = (unsigned char)(q & 255);
  int e2 = q * q;
  #pragma unroll
  for (int off = 32; off; off >>= 1) e2 += __shfl_down(e2, off);
  const int lane = d & 63, w = d >> 6;
  if (lane == 0) red[w] = e2;
  __syncthreads();
  if (d == 0) cinit[code] = -((red[0] + red[1] + red[2] + red[3]) >> 1);
  if (d < 64) {
    unsigned u = (unsigned)rb[4 * d] | ((unsigned)rb[4 * d + 1] << 8) |
                 ((unsigned)rb[4 * d + 2] << 16) | ((unsigned)rb[4 * d + 3] << 24);
    const int cs = (d >> 2) ^ (code & 15);   // XOR-swizzle 16B chunks within 256B row
    ((unsigned*)(eswz + code * 256))[(cs << 2) | (d & 3)] = u;
  }
}

// ============ K1: i8-MFMA score GEMM (exact int scores) + packed top-4 ============
// acc = 256*(x_q.e_q) - ||16 e_q||^2/2  (int, deterministic)
// key = (acc<<13) + code  -> top-4 per (row, lane-quarter) via min/max ladder

struct PList { int a, b, c, d; };

__device__ __forceinline__ void ladder(PList& P, int t) {
  int c0 = min(P.a, t); P.a = max(P.a, t);
  int c1 = min(P.b, c0); P.b = max(P.b, c0);
  int c2 = min(P.c, c1); P.c = max(P.c, c1);
  P.d = max(P.d, c2);
}

__device__ __forceinline__ void psel(PList& P, i32x4 acc, int cb) {
  int p0 = (acc[0] << 13) + cb;
  int p1 = (acc[1] << 13) + cb + 1;
  int p2 = (acc[2] << 13) + cb + 2;
  int p3 = (acc[3] << 13) + cb + 3;
  int h1 = max(p0, p1), l1 = min(p0, p1);
  int h2 = max(p2, p3), l2 = min(p2, p3);
  int t1 = max(h1, h2);
  int t2 = max(min(h1, h2), max(l1, l2));
  ladder(P, t1);
  if (__any(t2 > P.d)) ladder(P, t2);      // rare: 2 top-4 codes in same 4-tile
}

__device__ __forceinline__ int pk4(f32x4 v) {
  int r = 0;
  #pragma unroll
  for (int j = 0; j < 4; ++j) {
    float q = fminf(127.f, fmaxf(-127.f, rintf(16.f * v[j])));
    r |= ((int)q & 255) << (8 * j);
  }
  return r;
}

__global__ __launch_bounds__(256, 2) void k_gemm(const float* __restrict__ x,
                                                 const signed char* __restrict__ eswz,
                                                 const int* __restrict__ cinit,
                                                 unsigned short* __restrict__ cand) {
  __shared__ signed char ebuf[3][8192];      // ring: 3 slots x (32 codes x 256 k i8)
  __shared__ int ci_s[NCODE];                // 32KB C-init table
  const int tid = threadIdx.x;
  const int lane = tid & 63, wave = tid >> 6;
  const int q = lane >> 4, ln = lane & 15;
  const int wrow0 = blockIdx.x * 128 + wave * 32;

  // stage cinit (8 rounds) + code-tile 0 into slot 0
  #pragma unroll
  for (int r = 0; r < 8; ++r)
    gl_lds16(cinit + r * 1024 + tid * 4, &ci_s[r * 1024 + tid * 4]);
  gl_lds16(eswz + tid * 16, &ebuf[0][tid * 16]);
  gl_lds16(eswz + 4096 + tid * 16, &ebuf[0][4096 + tid * 16]);

  // x fragments quantized to i8 (scale 16), resident in VGPRs.
  // B layout (16x16x64): lane holds B[k = 64s + 16q + j][n = ln], j=0..15
  i32x4 xf[2][4];
  #pragma unroll
  for (int t = 0; t < 2; ++t) {
    const float* xr = x + (unsigned)(wrow0 + t * 16 + ln) * DIM;
    #pragma unroll
    for (int s = 0; s < 4; ++s) {
      i32x4 dw;
      #pragma unroll
      for (int d = 0; d < 4; ++d)
        dw[d] = pk4(*(const f32x4*)(xr + s * 64 + q * 16 + d * 4));
      xf[t][s] = dw;
    }
  }

  PList P0 = {INT_MIN, INT_MIN, INT_MIN, INT_MIN};
  PList P1 = P0;

  int slot = 0;
  #pragma unroll 1
  for (int it = 0; it < 256; ++it) {
    const int nslot = (slot + 1 == 3) ? 0 : slot + 1;
    const int tl = (it < 255) ? it + 1 : 255;           // clamp: tail reload harmless
    const signed char* src = eswz + (unsigned)tl * 8192;
    gl_lds16(src + tid * 16, &ebuf[nslot][tid * 16]);
    gl_lds16(src + 4096 + tid * 16, &ebuf[nslot][4096 + tid * 16]);

    // counted wait: 2 just-issued loads stay in flight; tile `it` is complete.
    asm volatile("s_waitcnt vmcnt(2)\n\ts_barrier" ::: "memory");

    #pragma unroll
    for (int c = 0; c < 2; ++c) {
      const int cbase = it * 32 + c * 16 + q * 4;
      i32x4 en = *(const i32x4*)&ci_s[cbase];           // broadcast, conflict-free
      i32x4 acc0 = en, acc1 = en;                       // C-init = -||16e||^2/2
      const signed char* eb = &ebuf[slot][c * 4096];
      #pragma unroll
      for (int s = 0; s < 4; ++s) {
        const int chunk = (4 * s + q) ^ ln;             // undo swizzle; even banks
        i32x4 ea = *(const i32x4*)&eb[ln * 256 + chunk * 16];
        acc0 = __builtin_amdgcn_mfma_i32_16x16x64_i8(ea, xf[0][s], acc0, 0, 0, 0);
        acc1 = __builtin_amdgcn_mfma_i32_16x16x64_i8(ea, xf[1][s], acc1, 0, 0, 0);
      }
      psel(P0, acc0, cbase);
      psel(P1, acc1, cbase);
    }
    slot = nslot;
  }

  // write 4 candidate codes per (row, quarter) as u16
  {
    const int row0 = wrow0 + ln;
    u32x2 pk;
    pk[0] = ((unsigned)P0.a & 8191u) | (((unsigned)P0.b & 8191u) << 16);
    pk[1] = ((unsigned)P0.c & 8191u) | (((unsigned)P0.d & 8191u) << 16);
    *(u32x2*)&cand[row0 * 16 + q * 4] = pk;
    const int row1 = wrow0 + 16 + ln;
    pk[0] = ((unsigned)P1.a & 8191u) | (((unsigned)P1.b & 8191u) << 16);
    pk[1] = ((unsigned)P1.c & 8191u) | (((unsigned)P1.d & 8191u) << 16);
    *(u32x2*)&cand[row1 * 16 + q * 4] = pk;
  }
}

// ============ K2: exact re-score of 16 candidates (f32 prod, f64 acc), top-5 ============
__global__ __launch_bounds__(256) void k_refine(const float* __restrict__ x,
                                                const float* __restrict__ embed,
                                                const unsigned short* __restrict__ cand,
                                                float* __restrict__ out_idx,
                                                int* __restrict__ idx5,
                                                float* __restrict__ w5,
                                                float* __restrict__ enc_sum,
                                                unsigned* __restrict__ cnt) {
  __shared__ float sh[4][16][66];
  const int wave = threadIdx.x >> 6, l = threadIdx.x & 63;
  const int row = blockIdx.x * 4 + wave;
  const float* xr = x + (unsigned)row * DIM;
  const float t0 = -2.f * xr[l], t1 = -2.f * xr[l + 64];
  const float t2 = -2.f * xr[l + 128], t3 = -2.f * xr[l + 192];

  int cd[16];
  const unsigned* cp = (const unsigned*)(cand + row * 16);
  #pragma unroll
  for (int i = 0; i < 8; ++i) {
    unsigned v = cp[i];
    cd[2 * i] = (int)(v & 0xFFFFu);
    cd[2 * i + 1] = (int)(v >> 16);
  }

  // per-lane partial of (||e||^2 - 2 x.e) over this lane's 4 dims, all 16 cands
  #pragma unroll
  for (int ci = 0; ci < 16; ++ci) {
    const float* er = embed + (unsigned)cd[ci] * DIM;
    const float e0 = er[l], e1 = er[l + 64], e2 = er[l + 128], e3 = er[l + 192];
    float p = e0 * (e0 + t0);
    p = fmaf(e1, e1 + t1, p);
    p = fmaf(e2, e2 + t2, p);
    p = fmaf(e3, e3 + t3, p);
    sh[wave][ci][l] = p;
  }
  asm volatile("s_waitcnt lgkmcnt(0)" ::: "memory");

  // transpose-reduce: cand c = l>>2 summed by 4 lanes (sub = l&3), f64 accumulate
  const int c = l >> 2, sub = l & 3;
  const float* sp = &sh[wave][c][sub * 16];
  double s64 = 0.0;
  #pragma unroll
  for (int i = 0; i < 4; ++i) {
    f32x4 v = *(const f32x4*)(sp + i * 4);
    s64 += (double)v[0] + (double)v[1] + (double)v[2] + (double)v[3];
  }
  s64 += __shfl_xor(s64, 1);
  s64 += __shfl_xor(s64, 2);

  // broadcast: lane l gets score of cand (l&15)
  double sc = __shfl(s64, (l & 15) * 4);
  unsigned key = f2key((float)sc);
  const int myc = cd[l & 15];

  // wave-parallel top-5 within each 16-lane group (groups redundant)
  bool used = false;
  int codes[5]; float svals[5];
  #pragma unroll
  for (int j = 0; j < 5; ++j) {
    unsigned k = used ? 0xFFFFFFFFu : key;
    unsigned mm = k;
    #pragma unroll
    for (int off = 1; off < 16; off <<= 1) mm = min(mm, (unsigned)__shfl_xor((int)mm, off));
    int cc = (k == mm) ? myc : 0x7FFFFFFF;               // ties -> lower code
    #pragma unroll
    for (int off = 1; off < 16; off <<= 1) cc = min(cc, __shfl_xor(cc, off));
    used = used || (myc == cc);
    codes[j] = cc;
    svals[j] = key2f(mm);
  }

  float ex[5], sum = 0.f;
  #pragma unroll
  for (int j = 0; j < 5; ++j) { ex[j] = expf(-(svals[j] - svals[0])); sum += ex[j]; }
  const float inv = 1.f / sum;

  if (l == 0) {
    out_idx[row] = (float)codes[0];
    #pragma unroll
    for (int j = 0; j < 5; ++j) {
      float w = ex[j] * inv;
      idx5[row * 5 + j] = codes[j];
      w5[row * 5 + j] = w;
      atomicAdd(&enc_sum[codes[j]], w);
      atomicAdd(&cnt[codes[j]], 1u);
    }
  }
}

// ============ K3: scan counts -> CSR offsets, plus S factor ============
__global__ __launch_bounds__(256) void k_scan(const unsigned* __restrict__ cnt,
                                              unsigned* __restrict__ offs,
                                              unsigned* __restrict__ cursor,
                                              const float* __restrict__ enc_sum,
                                              const float* __restrict__ cluster_size,
                                              float* __restrict__ sfac) {
  __shared__ unsigned part[256];
  __shared__ double sred[256];
  const int t = threadIdx.x;
  unsigned s = 0;
  for (int i = 0; i < 32; ++i) s += cnt[t * 32 + i];
  part[t] = s;
  double ds = 0.0;
  for (int i = t; i < NCODE; i += 256)
    ds += 0.1 * (double)cluster_size[i] + 0.9 * (double)enc_sum[i];
  sred[t] = ds;
  __syncthreads();
  if (t == 0) {
    unsigned run = 0;
    for (int i = 0; i < 256; ++i) { unsigned tmp = part[i]; part[i] = run; run += tmp; }
    double S = 0.0;
    for (int i = 0; i < 256; ++i) S += sred[i];
    sfac[0] = (float)(S / (S + (double)NCODE * 1e-5));
  }
  __syncthreads();
  unsigned off = part[t];
  for (int i = 0; i < 32; ++i) {
    unsigned c = cnt[t * 32 + i];
    offs[t * 32 + i] = off;
    cursor[t * 32 + i] = off;
    off += c;
  }
}

// ============ K3b: fill CSR entries (meta = code<<16 | row) ============
__global__ __launch_bounds__(256) void k_fill(const int* __restrict__ idx5,
                                              const float* __restrict__ w5,
                                              unsigned* __restrict__ cursor,
                                              uint2* __restrict__ entries) {
  const int i = blockIdx.x * 256 + threadIdx.x;
  if (i >= NENT) return;
  const unsigned c = (unsigned)idx5[i];
  const float w = w5[i];
  const unsigned row = (unsigned)i / 5u;
  const unsigned slot = atomicAdd(&cursor[c], 1u);
  entries[slot] = make_uint2((c << 16) | row, __float_as_uint(w));
}

// ============ K4: flat segmented gather-accumulate (load-balanced) ============
__global__ __launch_bounds__(256) void k_accum2(const float* __restrict__ x,
                                                const uint2* __restrict__ entries,
                                                float* __restrict__ embsum) {
  __shared__ uint2 ent[ENT_PER_BLK];
  const int t = threadIdx.x;
  const unsigned base = blockIdx.x * ENT_PER_BLK;
  if (t < ENT_PER_BLK * 2)
    ((unsigned*)ent)[t] = ((const unsigned*)(entries + base))[t];
  __syncthreads();

  float acc = 0.f;
  unsigned cur = ent[0].x >> 16;
  #pragma unroll 8
  for (int i = 0; i < ENT_PER_BLK; ++i) {
    const uint2 e = ent[i];
    const unsigned code = e.x >> 16;
    const unsigned row = e.x & 0xFFFFu;
    const float w = __uint_as_float(e.y);
    if (code != cur) {                       // block-uniform branch
      atomicAdd(&embsum[cur * DIM + t], acc);
      acc = 0.f; cur = code;
    }
    acc = fmaf(w, x[row * DIM + t], acc);
  }
  atomicAdd(&embsum[cur * DIM + t], acc);
}

// ============ K4b: normalize embsum -> new_embed (in place) ============
__global__ __launch_bounds__(256) void k_norm(const float* __restrict__ embed_avg,
                                              const float* __restrict__ cluster_size,
                                              const float* __restrict__ enc_sum,
                                              const float* __restrict__ sfac,
                                              float* __restrict__ embsum /* -> newemb */) {
  const int k = blockIdx.x, d = threadIdx.x;
  const float ncs = 0.1f * cluster_size[k] + 0.9f * enc_sum[k];
  const float cs = (ncs + 1e-5f) * sfac[0];
  const unsigned o = (unsigned)k * DIM + d;
  embsum[o] = (0.1f * embed_avg[o] + 0.9f * embsum[o]) / cs;
}

// ============ K5: quantize = sum_j w_j * new_embed[idx_j] ============
__global__ __launch_bounds__(256) void k_quant(const int* __restrict__ idx5,
                                               const float* __restrict__ w5,
                                               const float* __restrict__ newemb,
                                               float* __restrict__ out) {
  const int d = threadIdx.x;
  const int rb = blockIdx.x * 16;
  #pragma unroll 2
  for (int r = 0; r < 16; ++r) {
    const int row = rb + r;
    float acc = 0.f;
    #pragma unroll
    for (int j = 0; j < 5; ++j)
      acc = fmaf(w5[row * 5 + j], newemb[(unsigned)idx5[row * 5 + j] * DIM + d], acc);
    out[(unsigned)row * DIM + d] = acc;
  }
}

extern "C" void kernel_launch(void* const* d_in, const int* in_sizes, int n_in,
                              void* d_out, int out_size, void* d_ws, size_t ws_size,
                              hipStream_t stream) {
  const float* x            = (const float*)d_in[0];   // [65536,256]
  const float* embed        = (const float*)d_in[1];   // [8192,256]
  const float* cluster_size = (const float*)d_in[2];   // [8192]
  // d_in[3] cluster_sum unused for outputs
  const float* embed_avg    = (const float*)d_in[4];   // [8192,256]

  char* w = (char*)d_ws;
  signed char*    eswz   = (signed char*)(w + WS_ESWZ);
  int*            cinit  = (int*)(w + WS_CINIT);
  unsigned short* cand   = (unsigned short*)(w + WS_CAND);
  int*            idx5   = (int*)(w + WS_IDX5);
  float*          w5     = (float*)(w + WS_W5);
  float*          encsum = (float*)(w + WS_ENCSUM);
  unsigned*       cnt    = (unsigned*)(w + WS_CNT);
  unsigned*       offs   = (unsigned*)(w + WS_OFFS);
  unsigned*       curs   = (unsigned*)(w + WS_CURS);
  float*          sfac   = (float*)(w + WS_SFAC);
  uint2*          entr   = (uint2*)(w + WS_ENTR);
  float*          embsum = (float*)(w + WS_NEWEMB);    // zeroed -> accum -> normalized in place

  float* out_q   = (float*)d_out;                 // [65536*256]
  float* out_idx = out_q + (size_t)NROWS * DIM;   // [65536] as float

  // zero enc_sum + cnt (adjacent 64KB) and embsum (8MB)
  hipMemsetAsync(w + WS_ENCSUM, 0, 65536, stream);
  hipMemsetAsync(w + WS_NEWEMB, 0, (size_t)NCODE * DIM * 4, stream);

  k_prep<<<NCODE, 256, 0, stream>>>(embed, eswz, cinit);
  k_gemm<<<512, 256, 0, stream>>>(x, eswz, cinit, cand);
  k_refine<<<NROWS / 4, 256, 0, stream>>>(x, embed, cand, out_idx, idx5, w5, encsum, cnt);
  k_scan<<<1, 256, 0, stream>>>(cnt, offs, curs, encsum, cluster_size, sfac);
  k_fill<<<(NENT + 255) / 256, 256, 0, stream>>>(idx5, w5, curs, entr);
  k_accum2<<<NENT / ENT_PER_BLK, 256, 0, stream>>>(x, entr, embsum);
  k_norm<<<NCODE, 256, 0, stream>>>(embed_avg, cluster_size, encsum, sfac, embsum);
  k_quant<<<NROWS / 16, 256, 0, stream>>>(idx5, w5, embsum, out_q);
}